// Round 13
// baseline (385.717 us; speedup 1.0000x reference)
//
#include <hip/hip_runtime.h>
#include <hip/hip_bf16.h>

typedef unsigned short u16;
typedef short bf16x8 __attribute__((ext_vector_type(8)));
typedef float f32x4 __attribute__((ext_vector_type(4)));
typedef float f32x16 __attribute__((ext_vector_type(16)));

#define N_    16
#define CIN   512
#define COUT  512
#define WD    512
#define P_    4096   // 64*64 spatial
#define CC    (COUT * CIN)

// ws layout (bytes)
#define OFF_S   0u
#define OFF_D   32768u
#define OFF_Z   65536u          // 1 KB zero page
#define OFF_WBT 131072u         // 9*512*512*2 = 4718592 B
#define OFF_XB  8388608u        // 16*4096*512*2 = 67108864 B
#define WS_NEED (OFF_XB + 67108864u)

__device__ __forceinline__ u16 f2bf(float f) {
  union { float f; unsigned u; } a; a.f = f;
  unsigned r = a.u + 0x7fffu + ((a.u >> 16) & 1u);   // RNE
  return (u16)(r >> 16);
}

__device__ __forceinline__ void gl_lds16(const u16* g, u16* l) {
  __builtin_amdgcn_global_load_lds(
      (const __attribute__((address_space(1))) void*)g,
      (__attribute__((address_space(3))) void*)l, 16, 0, 0);
}

// ---------- zero page ----------
__global__ void k_zero(float* z) { z[threadIdx.x] = 0.f; }

// ---------- s = w @ affine_w^T + affine_b ----------
__global__ __launch_bounds__(256) void k_affine(const float* __restrict__ w,
                                                const float* __restrict__ aw,
                                                const float* __restrict__ ab,
                                                float* __restrict__ s) {
  int idx = blockIdx.x * 256 + threadIdx.x;       // 16*512
  int n = idx >> 9, c = idx & 511;
  const float4* wr = (const float4*)(w + (size_t)n * WD);
  const float4* ar = (const float4*)(aw + (size_t)c * WD);
  float acc = 0.f;
#pragma unroll 4
  for (int k = 0; k < WD / 4; ++k) {
    float4 a = wr[k], b = ar[k];
    acc += a.x * b.x + a.y * b.y + a.z * b.z + a.w * b.w;
  }
  s[idx] = acc + ab[c];
}

// ---------- d = rsqrt(sum_i s^2 * w2 + 1e-8) ----------
__global__ __launch_bounds__(256) void k_demod(const float* __restrict__ s,
                                               const float* __restrict__ cw,
                                               float* __restrict__ d) {
  __shared__ float w2[CIN];
  int o = blockIdx.x;
  const float* wr = cw + (size_t)o * CIN * 9;
  for (int i = threadIdx.x; i < CIN; i += 256) {
    float acc = 0.f;
#pragma unroll
    for (int t = 0; t < 9; ++t) { float v = wr[i * 9 + t]; acc += v * v; }
    w2[i] = acc;
  }
  __syncthreads();
  int wave = threadIdx.x >> 6, lane = threadIdx.x & 63;
  for (int nn = wave; nn < N_; nn += 4) {
    float acc = 0.f;
    for (int i = lane; i < CIN; i += 64) {
      float sv = s[nn * CIN + i];
      acc += sv * sv * w2[i];
    }
#pragma unroll
    for (int off = 32; off > 0; off >>= 1) acc += __shfl_down(acc, off);
    if (lane == 0) {
      float a = acc + 1e-8f;
      float r = rsqrtf(a);
      r = r * (1.5f - 0.5f * a * r * r);   // Newton refine
      d[nn * COUT + o] = r;
    }
  }
}

// ---------- weights -> bf16, layout [tap][o][i] ----------
__global__ __launch_bounds__(256) void k_wprep(const float* __restrict__ cw,
                                               u16* __restrict__ wbt) {
  int idx = blockIdx.x * 256 + threadIdx.x;
  if (idx >= COUT * CIN * 9) return;
  int t = idx % 9; int oi = idx / 9; int i = oi & 511; int o = oi >> 9;
  wbt[((size_t)t * COUT + o) * CIN + i] = f2bf(cw[idx]);
}

// ---------- x * s -> bf16 NHWC  xb[n][p][c] ----------
__global__ __launch_bounds__(256) void k_xmod(const float* __restrict__ x,
                                              const float* __restrict__ s,
                                              u16* __restrict__ xb) {
  __shared__ float tile[64][65];
  int b = blockIdx.x;                 // 16 * 8 * 64
  int pt = b & 63; int ct = (b >> 6) & 7; int n = b >> 9;
  int c0 = ct * 64, p0 = pt * 64;
  const float* xp = x + ((size_t)n * CIN + c0) * P_ + p0;
  int t = threadIdx.x;
#pragma unroll
  for (int pass = 0; pass < 4; ++pass) {
    int r = pass * 16 + (t >> 4);
    int col4 = (t & 15);
    float4 v = *(const float4*)(xp + (size_t)r * P_ + col4 * 4);
    float sc = s[n * CIN + c0 + r];
    tile[r][col4 * 4 + 0] = v.x * sc;
    tile[r][col4 * 4 + 1] = v.y * sc;
    tile[r][col4 * 4 + 2] = v.z * sc;
    tile[r][col4 * 4 + 3] = v.w * sc;
  }
  __syncthreads();
  int p = t >> 2, cq = (t & 3) * 16;
  union { u16 us[16]; uint4 q[2]; } pk;
#pragma unroll
  for (int j = 0; j < 16; ++j) pk.us[j] = f2bf(tile[cq + j][p]);
  uint4* dst = (uint4*)(xb + ((size_t)n * P_ + p0 + p) * CIN + c0 + cq);
  dst[0] = pk.q[0];
  dst[1] = pk.q[1];
}

// ---------- main conv: implicit GEMM, 256x256 tile, BK=32, ring-4 LDS ----------
// 512 threads = 8 waves (2 wr x 4 wc); per-wave output 128x64 via 4mi x 2ni
// tiles of v_mfma_f32_32x32x16_bf16 (acc = 4x2 f32x16 = 128 regs; 16 MFMA
// per wave per BK=32 tile vs 32 with 16x16x32 — +15% matrix-pipe rate, m119).
// Same LDS layout/staging/swizzle as before; reads adapt: row = base+(l&31),
// phys slot = (kk*2 + (l>>5)) ^ (((l&31)>>1)&3). Wait ladder: lgkm(6)->ni0,
// lgkm(4)->ni1, lgkm(0)->mi2..3 cluster. vmcnt(8) gate, ring-4 depth-3.
__global__ __launch_bounds__(512, 2) void k_conv(const u16* __restrict__ xb,
                                                 const u16* __restrict__ wbt,
                                                 const u16* __restrict__ zp,
                                                 const float* __restrict__ dmod,
                                                 const float* __restrict__ cbias,
                                                 const float* __restrict__ noise,
                                                 const float* __restrict__ nstr,
                                                 float* __restrict__ out) {
  __shared__ u16 smA[4][8192];   // [buf][256 rows x 32 ch] 16 KB each
  __shared__ u16 smB[4][8192];

  // bijective XCD swizzle: nwg=512 -> XCD x gets n in {2x,2x+1}
  int bid = blockIdx.x;
  int wg = (bid & 7) * 64 + (bid >> 3);
  int n = wg >> 5;
  int rem = wg & 31;
  int ob = rem >> 4;            // 0..1   (out-ch block of 256)
  int pb = rem & 15;            // 0..15  (spatial block of 256 = 4 rows)

  int tid = threadIdx.x;
  int wv = tid >> 6, l = tid & 63;
  int wr = wv >> 2, wc = wv & 3;
  int l31 = l & 31, khalf = l >> 5;
  int sw = (l31 >> 1) & 3;                     // slot swizzle key
  int ks0 = (0 + khalf) ^ sw;                  // phys slot for kk=0
  int ks1 = (2 + khalf) ^ sw;                  // phys slot for kk=1

  // staging constants (unchanged)
  int srow = tid >> 2;                          // 0..127 row within group
  int lslot = (tid & 3) ^ ((tid >> 3) & 3);     // logical k-slot staged
  const u16* xbn = xb + (size_t)n * P_ * CIN;
  int hg[2], wgp[2];
#pragma unroll
  for (int g = 0; g < 2; ++g) {
    int ploc = g * 128 + srow;
    hg[g] = pb * 4 + (ploc >> 6);
    wgp[g] = ploc & 63;
  }
  const u16* srcA_base[2];
#pragma unroll
  for (int g = 0; g < 2; ++g)
    srcA_base[g] = wbt + (size_t)(ob * 256 + g * 128 + srow) * CIN + lslot * 8;

  auto stage_A = [&](int tt) {
    int b = tt & 3;
    int tapn = tt >> 4, cbn = tt & 15;
#pragma unroll
    for (int g = 0; g < 2; ++g) {
      const u16* src = srcA_base[g] + (size_t)tapn * CC + cbn * 32;
      gl_lds16(src, &smA[b][g * 4096 + wv * 512]);
    }
  };
  auto bsrc_for_tap = [&](int tapn, int g) -> const u16* {
    int dh = tapn < 3 ? -1 : (tapn < 6 ? 0 : 1);
    int dw = tapn - (dh + 1) * 3 - 1;
    int hh = hg[g] + dh, ww = wgp[g] + dw;
    bool val = ((unsigned)hh < 64u) && ((unsigned)ww < 64u);
    return val ? (xbn + ((size_t)((hh << 6) + ww)) * CIN + lslot * 8)
               : (zp + lslot * 8);
  };
  auto stage_B = [&](int tt) {
    int b = tt & 3;
    int tapn = tt >> 4, cbn = tt & 15;
#pragma unroll
    for (int g = 0; g < 2; ++g)
      gl_lds16(bsrc_for_tap(tapn, g) + cbn * 32, &smB[b][g * 4096 + wv * 512]);
  };

  f32x16 acc[4][2];
  f32x16 zz = {};
#pragma unroll
  for (int i = 0; i < 4; ++i)
#pragma unroll
    for (int j = 0; j < 2; ++j) acc[i][j] = zz;

  // prologue: stage tiles 0,1,2 (12 loads in flight; 4 per tile: A then B)
  stage_A(0); stage_B(0);
  stage_A(1); stage_B(1);
  stage_A(2); stage_B(2);

  // rolling source pointers for tile t+3 (init: tile 3 -> tap 0, cb 3)
  int tap3 = 0, cb3 = 3;
  const u16* rpA[2];
  const u16* rpB[2];
#pragma unroll
  for (int g = 0; g < 2; ++g) {
    rpA[g] = srcA_base[g] + 3 * 32;
    rpB[g] = bsrc_for_tap(0, g) + 3 * 32;
  }

  for (int t = 0; t < 144; ++t) {      // 9 taps * 16 cb
    int b = t & 3;
    int bs = (t + 3) & 3;
    // gate: tile-t loads retired everywhere after barrier
    if (t <= 141)      asm volatile("s_waitcnt vmcnt(8)" ::: "memory");
    else if (t == 142) asm volatile("s_waitcnt vmcnt(4)" ::: "memory");
    else               asm volatile("s_waitcnt vmcnt(0)" ::: "memory");
    __builtin_amdgcn_s_barrier();
    __builtin_amdgcn_sched_barrier(0);

    const u16* A = smA[b];
    const u16* B = smB[b];

    // ---- issue 12 frag reads; pinned order: AfL(4) | Bf0(2) | Bf1(2) | AfH(4)
    bf16x8 AfL[2][2], AfH[2][2], Bf[2][2];
#pragma unroll
    for (int mi = 0; mi < 2; ++mi) {
      int rowA = (wr * 128 + mi * 32 + l31) * 32;
      AfL[mi][0] = *(const bf16x8*)&A[rowA + ks0 * 8];
      AfL[mi][1] = *(const bf16x8*)&A[rowA + ks1 * 8];
    }
    __builtin_amdgcn_sched_barrier(0);
    {
      int rowB = (wc * 64 + l31) * 32;
      Bf[0][0] = *(const bf16x8*)&B[rowB + ks0 * 8];
      Bf[0][1] = *(const bf16x8*)&B[rowB + ks1 * 8];
    }
    __builtin_amdgcn_sched_barrier(0);
    {
      int rowB = (wc * 64 + 32 + l31) * 32;
      Bf[1][0] = *(const bf16x8*)&B[rowB + ks0 * 8];
      Bf[1][1] = *(const bf16x8*)&B[rowB + ks1 * 8];
    }
    __builtin_amdgcn_sched_barrier(0);
#pragma unroll
    for (int mi = 0; mi < 2; ++mi) {
      int rowA = (wr * 128 + (mi + 2) * 32 + l31) * 32;
      AfH[mi][0] = *(const bf16x8*)&A[rowA + ks0 * 8];
      AfH[mi][1] = *(const bf16x8*)&A[rowA + ks1 * 8];
    }
    __builtin_amdgcn_sched_barrier(0);

    // ---- stage tile t+3 (vmcnt ops only) + pointer advance ----
    if (t <= 140) {
#pragma unroll
      for (int g = 0; g < 2; ++g)
        gl_lds16(rpA[g], &smA[bs][g * 4096 + wv * 512]);
#pragma unroll
      for (int g = 0; g < 2; ++g)
        gl_lds16(rpB[g], &smB[bs][g * 4096 + wv * 512]);
      cb3++;
      if (cb3 == 16) {
        cb3 = 0; tap3++;
#pragma unroll
        for (int g = 0; g < 2; ++g) {
          rpA[g] = srcA_base[g] + (size_t)tap3 * CC;
          rpB[g] = bsrc_for_tap(tap3, g);
        }
      } else {
#pragma unroll
        for (int g = 0; g < 2; ++g) { rpA[g] += 32; rpB[g] += 32; }
      }
    }
    __builtin_amdgcn_sched_barrier(0);

    // ---- pipelined MFMA: ni0 after 6 outstanding, ni1 after 4, AfH after 0
    __builtin_amdgcn_s_setprio(1);
    asm volatile("s_waitcnt lgkmcnt(6)" ::: "memory");
    __builtin_amdgcn_sched_barrier(0);
#pragma unroll
    for (int mi = 0; mi < 2; ++mi) {
      acc[mi][0] = __builtin_amdgcn_mfma_f32_32x32x16_bf16(AfL[mi][0], Bf[0][0], acc[mi][0], 0, 0, 0);
      acc[mi][0] = __builtin_amdgcn_mfma_f32_32x32x16_bf16(AfL[mi][1], Bf[0][1], acc[mi][0], 0, 0, 0);
    }
    asm volatile("s_waitcnt lgkmcnt(4)" ::: "memory");
    __builtin_amdgcn_sched_barrier(0);
#pragma unroll
    for (int mi = 0; mi < 2; ++mi) {
      acc[mi][1] = __builtin_amdgcn_mfma_f32_32x32x16_bf16(AfL[mi][0], Bf[1][0], acc[mi][1], 0, 0, 0);
      acc[mi][1] = __builtin_amdgcn_mfma_f32_32x32x16_bf16(AfL[mi][1], Bf[1][1], acc[mi][1], 0, 0, 0);
    }
    asm volatile("s_waitcnt lgkmcnt(0)" ::: "memory");
    __builtin_amdgcn_sched_barrier(0);
#pragma unroll
    for (int mi = 0; mi < 2; ++mi) {
#pragma unroll
      for (int ni = 0; ni < 2; ++ni) {
        acc[mi + 2][ni] = __builtin_amdgcn_mfma_f32_32x32x16_bf16(AfH[mi][0], Bf[ni][0], acc[mi + 2][ni], 0, 0, 0);
        acc[mi + 2][ni] = __builtin_amdgcn_mfma_f32_32x32x16_bf16(AfH[mi][1], Bf[ni][1], acc[mi + 2][ni], 0, 0, 0);
      }
    }
    __builtin_amdgcn_s_setprio(0);
  }

  // epilogue: demod scale + bias + noise + LeakyReLU(0.2)
  // C/D map (32x32): col = lane&31, row = (reg&3) + 8*(reg>>2) + 4*(lane>>5)
  float ns = nstr[0];
  const float* noise_n = noise + (size_t)n * P_;
  float nz[2];
#pragma unroll
  for (int ni = 0; ni < 2; ++ni)
    nz[ni] = noise_n[pb * 256 + wc * 64 + ni * 32 + l31] * ns;

#pragma unroll
  for (int mi = 0; mi < 4; ++mi) {
#pragma unroll
    for (int rg = 0; rg < 4; ++rg) {
#pragma unroll
      for (int rs = 0; rs < 4; ++rs) {
        int reg = rg * 4 + rs;
        int o = ob * 256 + wr * 128 + mi * 32 + rs + rg * 8 + khalf * 4;
        float dv = dmod[n * COUT + o];
        float bv = cbias[o];
        float* orow = out + ((size_t)(n * COUT + o)) * P_ + pb * 256 + wc * 64 + l31;
#pragma unroll
        for (int ni = 0; ni < 2; ++ni) {
          float v = acc[mi][ni][reg] * dv + bv + nz[ni];
          orow[ni * 32] = v >= 0.f ? v : 0.2f * v;
        }
      }
    }
  }
}

// ---------- fallback (small ws): direct conv ----------
__global__ __launch_bounds__(64) void k_conv_naive(const float* __restrict__ x,
                                                   const float* __restrict__ cw,
                                                   const float* __restrict__ cbias,
                                                   const float* __restrict__ noise,
                                                   const float* __restrict__ nstr,
                                                   const float* __restrict__ s,
                                                   const float* __restrict__ d,
                                                   float* __restrict__ out) {
  int bid = blockIdx.x;                 // 16*512*64 = (n,o,h)
  int h = bid & 63; int o = (bid >> 6) & 511; int n = bid >> 15;
  int wcol = threadIdx.x;
  float acc = 0.f;
  for (int i = 0; i < CIN; ++i) {
    float sv = s[n * CIN + i];
    const float* xrow = x + ((size_t)(n * CIN + i)) * P_;
    const float* wrp = cw + ((size_t)o * CIN + i) * 9;
#pragma unroll
    for (int t = 0; t < 9; ++t) {
      int hh = h + t / 3 - 1, ww = wcol + t % 3 - 1;
      float xv = ((unsigned)hh < 64u && (unsigned)ww < 64u) ? xrow[hh * 64 + ww] : 0.f;
      acc += xv * sv * wrp[t];
    }
  }
  float v = acc * d[n * COUT + o] + cbias[o] + noise[(size_t)n * P_ + h * 64 + wcol] * nstr[0];
  out[((size_t)(n * COUT + o)) * P_ + h * 64 + wcol] = v >= 0.f ? v : 0.2f * v;
}

extern "C" void kernel_launch(void* const* d_in, const int* in_sizes, int n_in,
                              void* d_out, int out_size, void* d_ws, size_t ws_size,
                              hipStream_t stream) {
  const float* x    = (const float*)d_in[0];
  const float* w    = (const float*)d_in[1];
  const float* noise= (const float*)d_in[2];
  const float* aw   = (const float*)d_in[3];
  const float* ab   = (const float*)d_in[4];
  const float* nstr = (const float*)d_in[5];
  const float* cw   = (const float*)d_in[6];
  const float* cb   = (const float*)d_in[7];
  float* out = (float*)d_out;
  char* ws = (char*)d_ws;
  float* s = (float*)(ws + OFF_S);
  float* d = (float*)(ws + OFF_D);

  k_affine<<<(N_ * COUT) / 256, 256, 0, stream>>>(w, aw, ab, s);
  k_demod<<<COUT, 256, 0, stream>>>(s, cw, d);

  if (ws_size >= WS_NEED) {
    u16* zp  = (u16*)(ws + OFF_Z);
    u16* wbt = (u16*)(ws + OFF_WBT);
    u16* xbb = (u16*)(ws + OFF_XB);
    k_zero<<<1, 256, 0, stream>>>((float*)zp);
    k_wprep<<<(COUT * CIN * 9 + 255) / 256, 256, 0, stream>>>(cw, wbt);
    k_xmod<<<N_ * 8 * 64, 256, 0, stream>>>(x, s, xbb);
    k_conv<<<512, 512, 0, stream>>>(xbb, wbt, zp, d, cb, noise, nstr, out);
  } else {
    k_conv_naive<<<N_ * COUT * 64, 64, 0, stream>>>(x, cw, cb, noise, nstr, s, d, out);
  }
}

// Round 14
// 336.914 us; speedup vs baseline: 1.1449x; 1.1449x over previous
//
#include <hip/hip_runtime.h>
#include <hip/hip_bf16.h>

typedef unsigned short u16;
typedef short bf16x8 __attribute__((ext_vector_type(8)));
typedef float f32x4 __attribute__((ext_vector_type(4)));

#define N_    16
#define CIN   512
#define COUT  512
#define WD    512
#define P_    4096   // 64*64 spatial
#define CC    (COUT * CIN)

// ws layout (bytes)
#define OFF_S   0u
#define OFF_D   32768u
#define OFF_Z   65536u          // 1 KB zero page
#define OFF_WBT 131072u         // 9*512*512*2 = 4718592 B
#define OFF_XB  8388608u        // 16*4096*512*2 = 67108864 B
#define WS_NEED (OFF_XB + 67108864u)

__device__ __forceinline__ u16 f2bf(float f) {
  union { float f; unsigned u; } a; a.f = f;
  unsigned r = a.u + 0x7fffu + ((a.u >> 16) & 1u);   // RNE
  return (u16)(r >> 16);
}

__device__ __forceinline__ void gl_lds16(const u16* g, u16* l) {
  __builtin_amdgcn_global_load_lds(
      (const __attribute__((address_space(1))) void*)g,
      (__attribute__((address_space(3))) void*)l, 16, 0, 0);
}

// ---------- zero page ----------
__global__ void k_zero(float* z) { z[threadIdx.x] = 0.f; }

// ---------- s = w @ affine_w^T + affine_b ----------
__global__ __launch_bounds__(256) void k_affine(const float* __restrict__ w,
                                                const float* __restrict__ aw,
                                                const float* __restrict__ ab,
                                                float* __restrict__ s) {
  int idx = blockIdx.x * 256 + threadIdx.x;       // 16*512
  int n = idx >> 9, c = idx & 511;
  const float4* wr = (const float4*)(w + (size_t)n * WD);
  const float4* ar = (const float4*)(aw + (size_t)c * WD);
  float acc = 0.f;
#pragma unroll 4
  for (int k = 0; k < WD / 4; ++k) {
    float4 a = wr[k], b = ar[k];
    acc += a.x * b.x + a.y * b.y + a.z * b.z + a.w * b.w;
  }
  s[idx] = acc + ab[c];
}

// ---------- d = rsqrt(sum_i s^2 * w2 + 1e-8) ----------
__global__ __launch_bounds__(256) void k_demod(const float* __restrict__ s,
                                               const float* __restrict__ cw,
                                               float* __restrict__ d) {
  __shared__ float w2[CIN];
  int o = blockIdx.x;
  const float* wr = cw + (size_t)o * CIN * 9;
  for (int i = threadIdx.x; i < CIN; i += 256) {
    float acc = 0.f;
#pragma unroll
    for (int t = 0; t < 9; ++t) { float v = wr[i * 9 + t]; acc += v * v; }
    w2[i] = acc;
  }
  __syncthreads();
  int wave = threadIdx.x >> 6, lane = threadIdx.x & 63;
  for (int nn = wave; nn < N_; nn += 4) {
    float acc = 0.f;
    for (int i = lane; i < CIN; i += 64) {
      float sv = s[nn * CIN + i];
      acc += sv * sv * w2[i];
    }
#pragma unroll
    for (int off = 32; off > 0; off >>= 1) acc += __shfl_down(acc, off);
    if (lane == 0) {
      float a = acc + 1e-8f;
      float r = rsqrtf(a);
      r = r * (1.5f - 0.5f * a * r * r);   // Newton refine
      d[nn * COUT + o] = r;
    }
  }
}

// ---------- weights -> bf16, layout [tap][o][i] ----------
__global__ __launch_bounds__(256) void k_wprep(const float* __restrict__ cw,
                                               u16* __restrict__ wbt) {
  int idx = blockIdx.x * 256 + threadIdx.x;
  if (idx >= COUT * CIN * 9) return;
  int t = idx % 9; int oi = idx / 9; int i = oi & 511; int o = oi >> 9;
  wbt[((size_t)t * COUT + o) * CIN + i] = f2bf(cw[idx]);
}

// ---------- x * s -> bf16 NHWC  xb[n][p][c] ----------
__global__ __launch_bounds__(256) void k_xmod(const float* __restrict__ x,
                                              const float* __restrict__ s,
                                              u16* __restrict__ xb) {
  __shared__ float tile[64][65];
  int b = blockIdx.x;                 // 16 * 8 * 64
  int pt = b & 63; int ct = (b >> 6) & 7; int n = b >> 9;
  int c0 = ct * 64, p0 = pt * 64;
  const float* xp = x + ((size_t)n * CIN + c0) * P_ + p0;
  int t = threadIdx.x;
#pragma unroll
  for (int pass = 0; pass < 4; ++pass) {
    int r = pass * 16 + (t >> 4);
    int col4 = (t & 15);
    float4 v = *(const float4*)(xp + (size_t)r * P_ + col4 * 4);
    float sc = s[n * CIN + c0 + r];
    tile[r][col4 * 4 + 0] = v.x * sc;
    tile[r][col4 * 4 + 1] = v.y * sc;
    tile[r][col4 * 4 + 2] = v.z * sc;
    tile[r][col4 * 4 + 3] = v.w * sc;
  }
  __syncthreads();
  int p = t >> 2, cq = (t & 3) * 16;
  union { u16 us[16]; uint4 q[2]; } pk;
#pragma unroll
  for (int j = 0; j < 16; ++j) pk.us[j] = f2bf(tile[cq + j][p]);
  uint4* dst = (uint4*)(xb + ((size_t)n * P_ + p0 + p) * CIN + c0 + cq);
  dst[0] = pk.q[0];
  dst[1] = pk.q[1];
}

// ---------- main conv: implicit GEMM, 256x256 tile, BK=32, ring-4 LDS ----------
// 512 threads = 8 waves (2 wr x 4 wc); per-wave output 128x64.
// 2-tile barrier interval: one {vmcnt(0); s_barrier} per tiles (a=2k, b=2k+1)
// confirms BOTH tiles staged block-wide. Tile-b's 12 ds_reads are issued
// mid-interval and land under tile-a's second MFMA cluster (LDS pipe serves
// b's reads while matrix pipe runs a-acc1) — pipe overlap without extra
// gates. In-order DS ladders: a-acc0 lgkm(7-ni); a-acc1 lgkm(8); b-acc0
// lgkm(7-ni); b-acc1 lgkm(0). Stages (tiles a+2, b+2) issue mid-interval;
// ring-4; barrier count = 1 per 64 MFMA.
__global__ __launch_bounds__(512, 2) void k_conv(const u16* __restrict__ xb,
                                                 const u16* __restrict__ wbt,
                                                 const u16* __restrict__ zp,
                                                 const float* __restrict__ dmod,
                                                 const float* __restrict__ cbias,
                                                 const float* __restrict__ noise,
                                                 const float* __restrict__ nstr,
                                                 float* __restrict__ out) {
  __shared__ u16 smA[4][8192];   // [buf][256 rows x 32 ch] 16 KB each
  __shared__ u16 smB[4][8192];

  // bijective XCD swizzle: nwg=512 -> XCD x gets n in {2x,2x+1}
  int bid = blockIdx.x;
  int wg = (bid & 7) * 64 + (bid >> 3);
  int n = wg >> 5;
  int rem = wg & 31;
  int ob = rem >> 4;            // 0..1   (out-ch block of 256)
  int pb = rem & 15;            // 0..15  (spatial block of 256 = 4 rows)

  int tid = threadIdx.x;
  int wv = tid >> 6, l = tid & 63;
  int wr = wv >> 2, wc = wv & 3;
  int lrow = l & 15, kgrp = l >> 4;
  int prs = kgrp ^ ((lrow >> 1) & 3);          // read phys slot (swizzle)

  // staging constants
  int srow = tid >> 2;                          // 0..127 row within group
  int lslot = (tid & 3) ^ ((tid >> 3) & 3);     // logical k-slot staged
  const u16* xbn = xb + (size_t)n * P_ * CIN;
  int hg[2], wgp[2];
#pragma unroll
  for (int g = 0; g < 2; ++g) {
    int ploc = g * 128 + srow;
    hg[g] = pb * 4 + (ploc >> 6);
    wgp[g] = ploc & 63;
  }
  const u16* srcA_base[2];
#pragma unroll
  for (int g = 0; g < 2; ++g)
    srcA_base[g] = wbt + (size_t)(ob * 256 + g * 128 + srow) * CIN + lslot * 8;

  auto bsrc_for_tap = [&](int tapn, int g) -> const u16* {
    int dh = tapn < 3 ? -1 : (tapn < 6 ? 0 : 1);
    int dw = tapn - (dh + 1) * 3 - 1;
    int hh = hg[g] + dh, ww = wgp[g] + dw;
    bool val = ((unsigned)hh < 64u) && ((unsigned)ww < 64u);
    return val ? (xbn + ((size_t)((hh << 6) + ww)) * CIN + lslot * 8)
               : (zp + lslot * 8);
  };
  // from-scratch stagers (prologue only)
  auto stage_tile = [&](int tt) {
    int b = tt & 3;
    int tapn = tt >> 4, cbn = tt & 15;
#pragma unroll
    for (int g = 0; g < 2; ++g) {
      const u16* src = srcA_base[g] + (size_t)tapn * CC + cbn * 32;
      gl_lds16(src, &smA[b][g * 4096 + wv * 512]);
    }
#pragma unroll
    for (int g = 0; g < 2; ++g)
      gl_lds16(bsrc_for_tap(tapn, g) + cbn * 32, &smB[b][g * 4096 + wv * 512]);
  };

  f32x4 acc0[4][4], acc1[4][4];
  f32x4 zero = {0.f, 0.f, 0.f, 0.f};
#pragma unroll
  for (int i = 0; i < 4; ++i)
#pragma unroll
    for (int j = 0; j < 4; ++j) { acc0[i][j] = zero; acc1[i][j] = zero; }

  // prologue: stage tiles 0,1 (8 loads: A,B per tile in order)
  stage_tile(0);
  stage_tile(1);

  // rolling stage state: next tile to stage = 2 (tap 0, cb 2)
  int ts = 2, tap3 = 0, cb3 = 2;
  const u16* rpA[2];
  const u16* rpB[2];
#pragma unroll
  for (int g = 0; g < 2; ++g) {
    rpA[g] = srcA_base[g] + 2 * 32;
    rpB[g] = bsrc_for_tap(0, g) + 2 * 32;
  }
  auto stage_next = [&]() {
    int bs = ts & 3;
#pragma unroll
    for (int g = 0; g < 2; ++g)
      gl_lds16(rpA[g], &smA[bs][g * 4096 + wv * 512]);
#pragma unroll
    for (int g = 0; g < 2; ++g)
      gl_lds16(rpB[g], &smB[bs][g * 4096 + wv * 512]);
    ++ts;
    cb3++;
    if (cb3 == 16) {
      cb3 = 0; tap3++;
#pragma unroll
      for (int g = 0; g < 2; ++g) {
        rpA[g] = srcA_base[g] + (size_t)tap3 * CC;
        rpB[g] = bsrc_for_tap(tap3, g);
      }
    } else {
#pragma unroll
      for (int g = 0; g < 2; ++g) { rpA[g] += 32; rpB[g] += 32; }
    }
  };

  for (int k = 0; k < 72; ++k) {       // 72 intervals x 2 tiles = 144
    int a = 2 * k;
    const u16* A0 = smA[a & 3];
    const u16* B0 = smB[a & 3];
    const u16* A1 = smA[(a + 1) & 3];
    const u16* B1 = smB[(a + 1) & 3];

    // top gate: tiles a AND b staged block-wide after barrier
    asm volatile("s_waitcnt vmcnt(0)" ::: "memory");
    __builtin_amdgcn_s_barrier();
    __builtin_amdgcn_sched_barrier(0);

    bf16x8 Af0a[4], Bfa[4], Af1a[4], Af0b[4], Bfb[4], Af1b[4];

    // ---- tile-a reads (12), pinned: Af0a | Bfa | Af1a ----
#pragma unroll
    for (int mi = 0; mi < 4; ++mi)
      Af0a[mi] = *(const bf16x8*)&A0[(wr * 128 + mi * 16 + lrow) * 32 + prs * 8];
    __builtin_amdgcn_sched_barrier(0);
#pragma unroll
    for (int ni = 0; ni < 4; ++ni)
      Bfa[ni] = *(const bf16x8*)&B0[(wc * 64 + ni * 16 + lrow) * 32 + prs * 8];
    __builtin_amdgcn_sched_barrier(0);
#pragma unroll
    for (int mi = 0; mi < 4; ++mi)
      Af1a[mi] = *(const bf16x8*)&A0[(wr * 128 + 64 + mi * 16 + lrow) * 32 + prs * 8];
    __builtin_amdgcn_sched_barrier(0);

    // ---- stage tile a+2 (4 gl_lds, vmcnt only) ----
    if (k <= 70) stage_next();
    __builtin_amdgcn_sched_barrier(0);

    // ---- a-acc0: per-column ladder (col ni after 5+ni of a's 12 reads) ----
    __builtin_amdgcn_s_setprio(1);
#pragma unroll
    for (int ni = 0; ni < 4; ++ni) {
      if (ni == 0)      asm volatile("s_waitcnt lgkmcnt(7)" ::: "memory");
      else if (ni == 1) asm volatile("s_waitcnt lgkmcnt(6)" ::: "memory");
      else if (ni == 2) asm volatile("s_waitcnt lgkmcnt(5)" ::: "memory");
      else              asm volatile("s_waitcnt lgkmcnt(4)" ::: "memory");
      __builtin_amdgcn_sched_barrier(0);
#pragma unroll
      for (int mi = 0; mi < 4; ++mi)
        acc0[mi][ni] = __builtin_amdgcn_mfma_f32_16x16x32_bf16(
            Af0a[mi], Bfa[ni], acc0[mi][ni], 0, 0, 0);
    }
    __builtin_amdgcn_s_setprio(0);
    __builtin_amdgcn_sched_barrier(0);

    // ---- issue tile-b first 8 reads (fly under a-acc1) ----
#pragma unroll
    for (int mi = 0; mi < 4; ++mi)
      Af0b[mi] = *(const bf16x8*)&A1[(wr * 128 + mi * 16 + lrow) * 32 + prs * 8];
    __builtin_amdgcn_sched_barrier(0);
#pragma unroll
    for (int ni = 0; ni < 4; ++ni)
      Bfb[ni] = *(const bf16x8*)&B1[(wc * 64 + ni * 16 + lrow) * 32 + prs * 8];
    __builtin_amdgcn_sched_barrier(0);

    // ---- a-acc1: needs Af1a (8 youngest outstanding = b's 8 reads) ----
    __builtin_amdgcn_s_setprio(1);
    asm volatile("s_waitcnt lgkmcnt(8)" ::: "memory");
    __builtin_amdgcn_sched_barrier(0);
#pragma unroll
    for (int mi = 0; mi < 4; ++mi)
#pragma unroll
      for (int ni = 0; ni < 4; ++ni)
        acc1[mi][ni] = __builtin_amdgcn_mfma_f32_16x16x32_bf16(
            Af1a[mi], Bfa[ni], acc1[mi][ni], 0, 0, 0);
    __builtin_amdgcn_s_setprio(0);
    __builtin_amdgcn_sched_barrier(0);

    // ---- issue tile-b last 4 reads + stage tile b+2 ----
#pragma unroll
    for (int mi = 0; mi < 4; ++mi)
      Af1b[mi] = *(const bf16x8*)&A1[(wr * 128 + 64 + mi * 16 + lrow) * 32 + prs * 8];
    __builtin_amdgcn_sched_barrier(0);
    if (k <= 70) stage_next();
    __builtin_amdgcn_sched_barrier(0);

    // ---- b-acc0: per-column ladder over b's 12 reads ----
    __builtin_amdgcn_s_setprio(1);
#pragma unroll
    for (int ni = 0; ni < 4; ++ni) {
      if (ni == 0)      asm volatile("s_waitcnt lgkmcnt(7)" ::: "memory");
      else if (ni == 1) asm volatile("s_waitcnt lgkmcnt(6)" ::: "memory");
      else if (ni == 2) asm volatile("s_waitcnt lgkmcnt(5)" ::: "memory");
      else              asm volatile("s_waitcnt lgkmcnt(4)" ::: "memory");
      __builtin_amdgcn_sched_barrier(0);
#pragma unroll
      for (int mi = 0; mi < 4; ++mi)
        acc0[mi][ni] = __builtin_amdgcn_mfma_f32_16x16x32_bf16(
            Af0b[mi], Bfb[ni], acc0[mi][ni], 0, 0, 0);
    }

    // ---- b-acc1 ----
    asm volatile("s_waitcnt lgkmcnt(0)" ::: "memory");
    __builtin_amdgcn_sched_barrier(0);
#pragma unroll
    for (int mi = 0; mi < 4; ++mi)
#pragma unroll
      for (int ni = 0; ni < 4; ++ni)
        acc1[mi][ni] = __builtin_amdgcn_mfma_f32_16x16x32_bf16(
            Af1b[mi], Bfb[ni], acc1[mi][ni], 0, 0, 0);
    __builtin_amdgcn_s_setprio(0);
  }

  // epilogue: demod scale + bias + noise + LeakyReLU(0.2)
  float ns = nstr[0];
  const float* noise_n = noise + (size_t)n * P_;
  float nz[4];
#pragma unroll
  for (int ni = 0; ni < 4; ++ni)
    nz[ni] = noise_n[pb * 256 + wc * 64 + ni * 16 + lrow] * ns;

  auto epi = [&](f32x4 (&A_)[4][4], int qm) {
#pragma unroll
    for (int mi = 0; mi < 4; ++mi) {
      int o0 = ob * 256 + wr * 128 + qm * 64 + mi * 16 + kgrp * 4;
#pragma unroll
      for (int r = 0; r < 4; ++r) {
        int o = o0 + r;
        float dv = dmod[n * COUT + o];
        float bv = cbias[o];
        float* orow = out + ((size_t)(n * COUT + o)) * P_ + pb * 256 + wc * 64;
#pragma unroll
        for (int ni = 0; ni < 4; ++ni) {
          float v = A_[mi][ni][r] * dv + bv + nz[ni];
          orow[ni * 16 + lrow] = v >= 0.f ? v : 0.2f * v;
        }
      }
    }
  };
  epi(acc0, 0);
  epi(acc1, 1);
}

// ---------- fallback (small ws): direct conv ----------
__global__ __launch_bounds__(64) void k_conv_naive(const float* __restrict__ x,
                                                   const float* __restrict__ cw,
                                                   const float* __restrict__ cbias,
                                                   const float* __restrict__ noise,
                                                   const float* __restrict__ nstr,
                                                   const float* __restrict__ s,
                                                   const float* __restrict__ d,
                                                   float* __restrict__ out) {
  int bid = blockIdx.x;                 // 16*512*64 = (n,o,h)
  int h = bid & 63; int o = (bid >> 6) & 511; int n = bid >> 15;
  int wcol = threadIdx.x;
  float acc = 0.f;
  for (int i = 0; i < CIN; ++i) {
    float sv = s[n * CIN + i];
    const float* xrow = x + ((size_t)(n * CIN + i)) * P_;
    const float* wrp = cw + ((size_t)o * CIN + i) * 9;
#pragma unroll
    for (int t = 0; t < 9; ++t) {
      int hh = h + t / 3 - 1, ww = wcol + t % 3 - 1;
      float xv = ((unsigned)hh < 64u && (unsigned)ww < 64u) ? xrow[hh * 64 + ww] : 0.f;
      acc += xv * sv * wrp[t];
    }
  }
  float v = acc * d[n * COUT + o] + cbias[o] + noise[(size_t)n * P_ + h * 64 + wcol] * nstr[0];
  out[((size_t)(n * COUT + o)) * P_ + h * 64 + wcol] = v >= 0.f ? v : 0.2f * v;
}

extern "C" void kernel_launch(void* const* d_in, const int* in_sizes, int n_in,
                              void* d_out, int out_size, void* d_ws, size_t ws_size,
                              hipStream_t stream) {
  const float* x    = (const float*)d_in[0];
  const float* w    = (const float*)d_in[1];
  const float* noise= (const float*)d_in[2];
  const float* aw   = (const float*)d_in[3];
  const float* ab   = (const float*)d_in[4];
  const float* nstr = (const float*)d_in[5];
  const float* cw   = (const float*)d_in[6];
  const float* cb   = (const float*)d_in[7];
  float* out = (float*)d_out;
  char* ws = (char*)d_ws;
  float* s = (float*)(ws + OFF_S);
  float* d = (float*)(ws + OFF_D);

  k_affine<<<(N_ * COUT) / 256, 256, 0, stream>>>(w, aw, ab, s);
  k_demod<<<COUT, 256, 0, stream>>>(s, cw, d);

  if (ws_size >= WS_NEED) {
    u16* zp  = (u16*)(ws + OFF_Z);
    u16* wbt = (u16*)(ws + OFF_WBT);
    u16* xbb = (u16*)(ws + OFF_XB);
    k_zero<<<1, 256, 0, stream>>>((float*)zp);
    k_wprep<<<(COUT * CIN * 9 + 255) / 256, 256, 0, stream>>>(cw, wbt);
    k_xmod<<<N_ * 8 * 64, 256, 0, stream>>>(x, s, xbb);
    k_conv<<<512, 512, 0, stream>>>(xbb, wbt, zp, d, cb, noise, nstr, out);
  } else {
    k_conv_naive<<<N_ * COUT * 64, 64, 0, stream>>>(x, cw, cb, noise, nstr, s, d, out);
  }
}